// Round 12
// baseline (383.067 us; speedup 1.0000x reference)
//
#include <hip/hip_runtime.h>
#include <math.h>

// GatedSpikingReservoirStep — fp16-single MFMA fused kernel + fp64 fixup.
// Round 18 = round 17 resubmit (container failed twice pre-run; full audit:
// fallback path is byte-identical to r10 [ran clean, 227us] with the exact
// known-safe 38.8MB workspace footprint; padded path bounds re-derived, all
// regions disjoint, 43.5MB < 44MiB guard, 16B-aligned strides; no counted
// vmcnt / raw barriers anywhere. Infra flaked all session -> resubmit.)
// Theory (unchanged): MEMORY-CHANNEL DE-ALIASING. r0-r10: per-block K-step
// pinned at 4.3-5.1k cy across all schedules/occupancies/byte-counts; r4
// proved exposed latency is not the cost; all pipes idle. Never-varied
// variable: power-of-2 row strides. Each gld16 reads 16 rows x 64B at 1KB/
// 4KB stride -> with ~256B channel interleave all 16 rows hit one channel
// (bits >=12 only) -> ~16x serialization, capping staging at ~8 B/cy/CU.
// Fix: pad fp16 strides to XP=640 (1280B) / SP=2176 (4352B): rows rotate
// 5/17 granules -> 16 distinct channel phases per staging instruction.
// Single-variable vs r10 (128x128 tile, 512thr/8 waves, 64 VGPR, 2 blk/CU,
// r1-proven schedule, r0 swizzles, XCD chunks). Numerics untouched.

#define IDIM 512
#define DDIM 2048
#define MAXD 2560
#define BDIM 4096
#define LIST_CAP 262144
#define BAND 4e-3f

typedef __attribute__((ext_vector_type(4))) float f32x4;
typedef __attribute__((ext_vector_type(8))) _Float16 f16x8;

__device__ __forceinline__ void gld16(const unsigned short* g, unsigned short* l) {
    __builtin_amdgcn_global_load_lds((const __attribute__((address_space(1))) void*)g,
                                     (__attribute__((address_space(3))) void*)l,
                                     16, 0, 0);
}
__device__ __forceinline__ float sigf(float x) { return 1.0f / (1.0f + __expf(-x)); }

// ---------------------------------------------------------------------------
// convert: fp32 -> fp16 for X, Wc=[Win;Wgate], S=state[:, :2048], Wr with
// runtime row strides XP (X/Wc) and SP (S/Wr); zero out-pad; zero counter.
// 20480 blocks x 256 (float4 units).
// ---------------------------------------------------------------------------
__global__ __launch_bounds__(256) void convert_kernel(
    const float* __restrict__ x, const float* __restrict__ state,
    const float* __restrict__ win, const float* __restrict__ wgate,
    const float* __restrict__ wres,
    unsigned short* __restrict__ X16, unsigned short* __restrict__ S16,
    unsigned short* __restrict__ Wc16, unsigned short* __restrict__ Wr16,
    float* __restrict__ out, unsigned* __restrict__ cnt, int XP, int SP)
{
    int idx = blockIdx.x * 256 + threadIdx.x;
    if (idx == 0) *cnt = 0u;
    float4 v;
    unsigned short* p;
    long off;
    if (idx < 524288) {                    // X: 4096 rows x 128 f4
        int row = idx >> 7, c4 = idx & 127;
        v = ((const float4*)x)[idx];
        p = X16; off = (long)row * XP + c4 * 4;
    } else if (idx < 1572864) {            // Wc: 8192 rows x 128 f4
        int i = idx - 524288;
        int row = i >> 7, c4 = i & 127;
        v = (i < 262144) ? ((const float4*)win)[i] : ((const float4*)wgate)[i - 262144];
        p = Wc16; off = (long)row * XP + c4 * 4;
    } else if (idx < 3670016) {            // S: 4096 rows x 512 f4
        int i = idx - 1572864;
        int row = i >> 9, c4 = i & 511;
        v = *(const float4*)(state + (long)row * MAXD + c4 * 4);
        p = S16; off = (long)row * SP + c4 * 4;
    } else if (idx < 4718592) {            // Wr: 2048 rows x 512 f4
        int i = idx - 3670016;
        int row = i >> 9, c4 = i & 511;
        v = ((const float4*)wres)[i];
        p = Wr16; off = (long)row * SP + c4 * 4;
    } else {                               // zero out[:, 2048:2560]
        int i = idx - 4718592;
        int row = i >> 7, c4 = i & 127;
        *(float4*)(out + (long)row * MAXD + DDIM + c4 * 4) = make_float4(0.f, 0.f, 0.f, 0.f);
        return;
    }
    _Float16 h0 = (_Float16)v.x, h1 = (_Float16)v.y;
    _Float16 h2 = (_Float16)v.z, h3 = (_Float16)v.w;
    ushort4 hv;
    hv.x = *(unsigned short*)&h0; hv.y = *(unsigned short*)&h1;
    hv.z = *(unsigned short*)&h2; hv.w = *(unsigned short*)&h3;
    *(ushort4*)(p + off) = hv;
}

// ---------------------------------------------------------------------------
// fused_step: 5 GEMM phases (virtual K=4096) + gating epilogue, 128x128 tile.
// 512 thr / 8 waves arranged 2m x 4n; wave owns 64x32 (acc[4][2]+u[4][2]).
// BK=32, single 16KB LDS buffer. Per K-step: sync; each wave stages 16 A-rows
// + 16 B-rows (2 gld16); sync; plain LDS fragment reads; 8 MFMA. Identical to
// r10 except runtime row strides XP/SP (channel de-aliasing pads).
// ---------------------------------------------------------------------------
__global__ __launch_bounds__(512, 4) void fused_step(
    const unsigned short* __restrict__ X16, const unsigned short* __restrict__ S16,
    const unsigned short* __restrict__ Wc16, const unsigned short* __restrict__ Wr16,
    const float* __restrict__ state, float* __restrict__ out,
    unsigned* __restrict__ cnt, unsigned* __restrict__ list, int XP, int SP)
{
    __shared__ alignas(16) unsigned short lA[128 * 32];
    __shared__ alignas(16) unsigned short lB[128 * 32];
    const int t = threadIdx.x;
    const int wave = t >> 6, lane = t & 63;
    const int wm = wave >> 2, wn = wave & 3;             // 2m x 4n wave grid
    const int quad = lane >> 4, l16 = lane & 15;

    // bijective XCD swizzle: 512 blocks, tile grid 32m x 16n, 64 tiles/XCD
    const int bid = blockIdx.x;
    const int nb  = (bid & 7) * 64 + (bid >> 3);
    const int xcd = nb >> 6, lid = nb & 63;
    const int m0 = (((xcd >> 1) << 3) + (lid >> 3)) * 128;   // 32 m-tiles
    const int n0 = (((xcd & 1) << 3) + (lid & 7)) * 128;     // 16 n-tiles

    const int rowoff = lane >> 2;                         // 0..15
    const int kg = ((lane & 3) ^ ((lane >> 3) & 3)) * 8;  // write-side chunk swizzle (hw)
    const int krh = (quad ^ ((l16 >> 1) & 3)) * 8;        // read-side chunk (hw)

    f32x4 acc[4][2];
    f32x4 u[4][2];    // sum -> 0.2*tanh(i*sum) -> + 0.8*f*prev  (2 live sets)

    #pragma unroll
    for (int mi = 0; mi < 4; mi++)
        #pragma unroll
        for (int ni = 0; ni < 2; ni++)
            acc[mi][ni] = (f32x4)0.0f;

    auto phase = [&](const unsigned short* Ag, long ldA,
                     const unsigned short* Bg, long ldB, int klen) {
        const unsigned short* a0 = Ag + (long)(wave * 16 + rowoff) * ldA + kg;
        const unsigned short* b0 = Bg + (long)(wave * 16 + rowoff) * ldB + kg;
        unsigned short* dA = lA + wave * 512;             // 16 rows x 32 hw
        unsigned short* dB = lB + wave * 512;
        for (int k0 = 0; k0 < klen; k0 += 32) {
            __syncthreads();
            gld16(a0 + k0, dA);
            gld16(b0 + k0, dB);
            __syncthreads();
            f16x8 af[4], bf[2];
            #pragma unroll
            for (int mi = 0; mi < 4; mi++)
                af[mi] = *(const f16x8*)&lA[(wm * 64 + mi * 16 + l16) * 32 + krh];
            #pragma unroll
            for (int ni = 0; ni < 2; ni++)
                bf[ni] = *(const f16x8*)&lB[(wn * 32 + ni * 16 + l16) * 32 + krh];
            #pragma unroll
            for (int mi = 0; mi < 4; mi++)
                #pragma unroll
                for (int ni = 0; ni < 2; ni++)
                    acc[mi][ni] = __builtin_amdgcn_mfma_f32_16x16x32_f16(af[mi], bf[ni], acc[mi][ni], 0, 0, 0);
        }
    };

    // Phase 0: acc = prev @ Wres^T          (K = 2048)
    phase(S16 + (long)m0 * SP, SP, Wr16 + (long)n0 * SP, SP, DDIM);
    // Phase 1: acc += X @ Win^T  -> u = ip + rp   (K = 512)
    phase(X16 + (long)m0 * XP, XP, Wc16 + (long)n0 * XP, XP, IDIM);
    #pragma unroll
    for (int mi = 0; mi < 4; mi++)
        #pragma unroll
        for (int ni = 0; ni < 2; ni++) { u[mi][ni] = acc[mi][ni]; acc[mi][ni] = (f32x4)0.0f; }

    // Phase 2: acc = X @ Wg_i^T  -> u = 0.2*tanh(sig(acc)*u)
    phase(X16 + (long)m0 * XP, XP, Wc16 + (long)(DDIM + n0) * XP, XP, IDIM);
    #pragma unroll
    for (int mi = 0; mi < 4; mi++)
        #pragma unroll
        for (int ni = 0; ni < 2; ni++) {
            #pragma unroll
            for (int r = 0; r < 4; r++)
                u[mi][ni][r] = 0.2f * tanhf(sigf(acc[mi][ni][r]) * u[mi][ni][r]);
            acc[mi][ni] = (f32x4)0.0f;
        }

    // Phase 3: acc = X @ Wg_f^T  -> u += 0.8*sig(acc)*prev
    phase(X16 + (long)m0 * XP, XP, Wc16 + (long)(2 * DDIM + n0) * XP, XP, IDIM);
    #pragma unroll
    for (int mi = 0; mi < 4; mi++)
        #pragma unroll
        for (int ni = 0; ni < 2; ni++) {
            #pragma unroll
            for (int r = 0; r < 4; r++) {
                int row = m0 + wm * 64 + mi * 16 + quad * 4 + r;
                int col = n0 + wn * 32 + ni * 16 + l16;
                float prev = state[(long)row * MAXD + col];
                u[mi][ni][r] += 0.8f * sigf(acc[mi][ni][r]) * prev;
            }
            acc[mi][ni] = (f32x4)0.0f;
        }

    // Phase 4: acc = X @ Wg_o^T  -> ns = sig(acc)*u -> spike -> write
    phase(X16 + (long)m0 * XP, XP, Wc16 + (long)(3 * DDIM + n0) * XP, XP, IDIM);
    #pragma unroll
    for (int mi = 0; mi < 4; mi++)
        #pragma unroll
        for (int ni = 0; ni < 2; ni++) {
            #pragma unroll
            for (int r = 0; r < 4; r++) {
                int row = m0 + wm * 64 + mi * 16 + quad * 4 + r;
                int col = n0 + wn * 32 + ni * 16 + l16;
                float go = sigf(acc[mi][ni][r]);
                float ns = go * u[mi][ni][r];
                float ov = (ns > 0.5f) ? ns - 0.5f : ns;
                out[(long)row * MAXD + col] = ov;
                if (fabsf(ns - 0.5f) < BAND) {
                    unsigned pos = atomicAdd(cnt, 1u);
                    if (pos < LIST_CAP) list[pos] = (unsigned)(row * DDIM + col);
                }
            }
        }
}

// ---------------------------------------------------------------------------
// fixup: recompute flagged elements exactly in fp64. 16-lane groups
// (4 elements per wave), float4-vectorized loads, width-16 shuffles.
// ---------------------------------------------------------------------------
__global__ __launch_bounds__(256) void fixup_kernel(
    const float* __restrict__ x, const float* __restrict__ state,
    const float* __restrict__ win, const float* __restrict__ wres,
    const float* __restrict__ wgate,
    const unsigned* __restrict__ cnt, const unsigned* __restrict__ list,
    float* __restrict__ out)
{
    const int grp  = (blockIdx.x * 256 + threadIdx.x) >> 4;   // global 16-lane group
    const int l16  = threadIdx.x & 15;
    const int ngrp = gridDim.x * 16;
    unsigned n = *cnt;
    if (n > LIST_CAP) n = LIST_CAP;
    for (unsigned e = grp; e < n; e += ngrp) {
        unsigned rc = list[e];
        int row = rc >> 11, col = rc & 2047;
        double ip = 0.0, gi = 0.0, gf = 0.0, go = 0.0, rp = 0.0;
        const float* xr  = x + (long)row * IDIM;
        const float* wi  = win + (long)col * IDIM;
        const float* wgi = wgate + (long)col * IDIM;
        const float* wgf = wgate + (long)(DDIM + col) * IDIM;
        const float* wgo = wgate + (long)(2 * DDIM + col) * IDIM;
        #pragma unroll 2
        for (int k = l16 * 4; k < IDIM; k += 64) {
            float4 xv = *(const float4*)(xr + k);
            float4 a = *(const float4*)(wi + k);
            float4 b = *(const float4*)(wgi + k);
            float4 c = *(const float4*)(wgf + k);
            float4 d = *(const float4*)(wgo + k);
            ip += (double)xv.x * a.x + (double)xv.y * a.y + (double)xv.z * a.z + (double)xv.w * a.w;
            gi += (double)xv.x * b.x + (double)xv.y * b.y + (double)xv.z * b.z + (double)xv.w * b.w;
            gf += (double)xv.x * c.x + (double)xv.y * c.y + (double)xv.z * c.z + (double)xv.w * c.w;
            go += (double)xv.x * d.x + (double)xv.y * d.y + (double)xv.z * d.z + (double)xv.w * d.w;
        }
        const float* sr = state + (long)row * MAXD;
        const float* wr_ = wres + (long)col * DDIM;
        #pragma unroll 4
        for (int k = l16 * 4; k < DDIM; k += 64) {
            float4 sv = *(const float4*)(sr + k);
            float4 wv = *(const float4*)(wr_ + k);
            rp += (double)sv.x * wv.x + (double)sv.y * wv.y + (double)sv.z * wv.z + (double)sv.w * wv.w;
        }
        #pragma unroll
        for (int o = 8; o > 0; o >>= 1) {
            ip += __shfl_down(ip, o, 16);
            gi += __shfl_down(gi, o, 16);
            gf += __shfl_down(gf, o, 16);
            go += __shfl_down(go, o, 16);
            rp += __shfl_down(rp, o, 16);
        }
        if (l16 == 0) {
            double si = 1.0 / (1.0 + exp(-gi));
            double sf = 1.0 / (1.0 + exp(-gf));
            double so = 1.0 / (1.0 + exp(-go));
            double prev = (double)state[(long)row * MAXD + col];
            double ns = so * (0.8 * sf * prev + 0.2 * tanh(si * (ip + rp)));
            if (ns > 0.5) ns -= 0.5;
            out[(long)row * MAXD + col] = (float)ns;
        }
    }
}

extern "C" void kernel_launch(void* const* d_in, const int* in_sizes, int n_in,
                              void* d_out, int out_size, void* d_ws, size_t ws_size,
                              hipStream_t stream) {
    const float* x     = (const float*)d_in[0];   // (4096, 512)
    const float* state = (const float*)d_in[1];   // (4096, 2560)
    const float* win   = (const float*)d_in[2];   // (2048, 512)
    const float* wres  = (const float*)d_in[3];   // (2048, 2048)
    const float* wgate = (const float*)d_in[4];   // (6144, 512)
    float* out = (float*)d_out;

    // channel de-aliasing pads (rows rotate 256B through the channel hash);
    // falls back to exact r10 strides if the workspace is too small.
    const int pad = (ws_size >= (44ll << 20)) ? 1 : 0;
    const int XP = pad ? 640 : 512;    // X / Wc row stride (halfwords)
    const int SP = pad ? 2176 : 2048;  // S / Wr row stride (halfwords)

    char* ws = (char*)d_ws;
    long oX = 0;
    long oW = oX + 4096L * XP * 2;     // Wc after X
    long oS = oW + 8192L * XP * 2;     // S after Wc
    long oR = oS + 4096L * SP * 2;     // Wr after S
    long oE = oR + 2048L * SP * 2;     // scalars after Wr
    oE = (oE + 255) & ~255L;
    unsigned short* X16  = (unsigned short*)(ws + oX);
    unsigned short* Wc16 = (unsigned short*)(ws + oW);
    unsigned short* S16  = (unsigned short*)(ws + oS);
    unsigned short* Wr16 = (unsigned short*)(ws + oR);
    unsigned* cnt  = (unsigned*)(ws + oE);
    unsigned* list = (unsigned*)(ws + oE + 16);

    convert_kernel<<<dim3(20480), dim3(256), 0, stream>>>(
        x, state, win, wgate, wres, X16, S16, Wc16, Wr16, out, cnt, XP, SP);

    fused_step<<<dim3(512), dim3(512), 0, stream>>>(
        X16, S16, Wc16, Wr16, state, out, cnt, list, XP, SP);

    fixup_kernel<<<dim3(1024), dim3(256), 0, stream>>>(
        x, state, win, wres, wgate, cnt, list, out);
}

// Round 13
// 336.420 us; speedup vs baseline: 1.1387x; 1.1387x over previous
//
#include <hip/hip_runtime.h>
#include <math.h>

// GatedSpikingReservoirStep — fp16-single MFMA fused kernel + fp64 fixup.
// Round 19: FIXUP BANDWIDTH. r12 falsified channel de-aliasing — completing
// the sweep: schedule(r1-r4), barriers(r5), occupancy(r6), bytes(r9),
// strides(r12) all falsified; fused_step floor ~227us (r10 config = best).
// New accounting: total-fused = 150us in BOTH r9 and r10, unmoved by 4x
// fixup parallelism -> fixup is BANDWIDTH-bound: 22k flagged x 26KB
// scattered fp32 re-reads (state 8K + wres 8K + x 2K + 4 gate rows 8K)
// ~570MB ~ 120us. 62% of that (W-data) depends only on col.
// Fix: bucket flagged elements BY COLUMN at append time (cnt[2048] +
// 96-deep buckets + overflow list for hot cols -> correctness
// unconditional); fixup = 2048 blocks, block c loads its 16KB W into LDS
// ONCE, each element then costs 10KB (x+state rows, L3-warm from fused).
// Traffic 570 -> ~260MB. Identical flag set + fp64 math -> absmax
// bit-identical. fused_step = r10 EXACT (227us) except the append.

#define IDIM 512
#define DDIM 2048
#define MAXD 2560
#define BDIM 4096
#define BCAP 96
#define OCAP 262144
#define BAND 4e-3f

typedef __attribute__((ext_vector_type(4))) float f32x4;
typedef __attribute__((ext_vector_type(8))) _Float16 f16x8;

__device__ __forceinline__ void gld16(const unsigned short* g, unsigned short* l) {
    __builtin_amdgcn_global_load_lds((const __attribute__((address_space(1))) void*)g,
                                     (__attribute__((address_space(3))) void*)l,
                                     16, 0, 0);
}
__device__ __forceinline__ float sigf(float x) { return 1.0f / (1.0f + __expf(-x)); }

// ---------------------------------------------------------------------------
// convert: fp32 -> fp16 for X, S=state[:, :2048], Wc=[Win;Wgate], Wr;
// zero out-pad; zero per-col flag counters. 20480 blocks x 256 (float4 units).
// ---------------------------------------------------------------------------
__global__ __launch_bounds__(256) void convert_kernel(
    const float* __restrict__ x, const float* __restrict__ state,
    const float* __restrict__ win, const float* __restrict__ wgate,
    const float* __restrict__ wres,
    unsigned short* __restrict__ X16, unsigned short* __restrict__ S16,
    unsigned short* __restrict__ Wc16, unsigned short* __restrict__ Wr16,
    float* __restrict__ out, unsigned* __restrict__ cntA)
{
    int idx = blockIdx.x * 256 + threadIdx.x;
    if (idx < 2052) cntA[idx] = 0u;      // 2048 col counters + overflow counter
    float4 v;
    unsigned short* p;
    long off;
    if (idx < 524288) {
        v = ((const float4*)x)[idx];
        p = X16; off = (long)idx * 4;
    } else if (idx < 2621440) {
        int i = idx - 524288;
        int row = i >> 9, c4 = i & 511;
        v = *(const float4*)(state + (long)row * MAXD + c4 * 4);
        p = S16; off = (long)i * 4;
    } else if (idx < 3670016) {
        int i = idx - 2621440;
        v = (i < 262144) ? ((const float4*)win)[i] : ((const float4*)wgate)[i - 262144];
        p = Wc16; off = (long)i * 4;
    } else if (idx < 4718592) {
        int i = idx - 3670016;
        v = ((const float4*)wres)[i];
        p = Wr16; off = (long)i * 4;
    } else {
        int i = idx - 4718592;
        int row = i >> 7, c4 = i & 127;
        *(float4*)(out + (long)row * MAXD + DDIM + c4 * 4) = make_float4(0.f, 0.f, 0.f, 0.f);
        return;
    }
    _Float16 h0 = (_Float16)v.x, h1 = (_Float16)v.y;
    _Float16 h2 = (_Float16)v.z, h3 = (_Float16)v.w;
    ushort4 hv;
    hv.x = *(unsigned short*)&h0; hv.y = *(unsigned short*)&h1;
    hv.z = *(unsigned short*)&h2; hv.w = *(unsigned short*)&h3;
    *(ushort4*)(p + off) = hv;
}

// ---------------------------------------------------------------------------
// fused_step: 5 GEMM phases (virtual K=4096) + gating epilogue, 128x128 tile.
// r10 EXACT (best measured, 227us): 512 thr / 8 waves 2m x 4n, wave owns
// 64x32 (acc[4][2]+u[4][2], 64 VGPR), BK=32, single 16KB LDS buffer,
// sync/gld16/sync/read/mfma, r0 chunk-XOR swizzle, XCD chunk mapping.
// Only change: flag append goes to per-col buckets (+ overflow list).
// ---------------------------------------------------------------------------
__global__ __launch_bounds__(512, 4) void fused_step(
    const unsigned short* __restrict__ X16, const unsigned short* __restrict__ S16,
    const unsigned short* __restrict__ Wc16, const unsigned short* __restrict__ Wr16,
    const float* __restrict__ state, float* __restrict__ out,
    unsigned* __restrict__ cntA, unsigned* __restrict__ bl, unsigned* __restrict__ ol)
{
    __shared__ alignas(16) unsigned short lA[128 * 32];
    __shared__ alignas(16) unsigned short lB[128 * 32];
    const int t = threadIdx.x;
    const int wave = t >> 6, lane = t & 63;
    const int wm = wave >> 2, wn = wave & 3;             // 2m x 4n wave grid
    const int quad = lane >> 4, l16 = lane & 15;

    // bijective XCD swizzle: 512 blocks, tile grid 32m x 16n, 64 tiles/XCD
    const int bid = blockIdx.x;
    const int nb  = (bid & 7) * 64 + (bid >> 3);
    const int xcd = nb >> 6, lid = nb & 63;
    const int m0 = (((xcd >> 1) << 3) + (lid >> 3)) * 128;   // 32 m-tiles
    const int n0 = (((xcd & 1) << 3) + (lid & 7)) * 128;     // 16 n-tiles

    const int rowoff = lane >> 2;                         // 0..15
    const int kg = ((lane & 3) ^ ((lane >> 3) & 3)) * 8;  // write-side chunk swizzle (hw)
    const int krh = (quad ^ ((l16 >> 1) & 3)) * 8;        // read-side chunk (hw)

    f32x4 acc[4][2];
    f32x4 u[4][2];    // sum -> 0.2*tanh(i*sum) -> + 0.8*f*prev  (2 live sets)

    #pragma unroll
    for (int mi = 0; mi < 4; mi++)
        #pragma unroll
        for (int ni = 0; ni < 2; ni++)
            acc[mi][ni] = (f32x4)0.0f;

    auto phase = [&](const unsigned short* Ag, long ldA,
                     const unsigned short* Bg, long ldB, int klen) {
        const unsigned short* a0 = Ag + (long)(wave * 16 + rowoff) * ldA + kg;
        const unsigned short* b0 = Bg + (long)(wave * 16 + rowoff) * ldB + kg;
        unsigned short* dA = lA + wave * 512;             // 16 rows x 32 hw
        unsigned short* dB = lB + wave * 512;
        for (int k0 = 0; k0 < klen; k0 += 32) {
            __syncthreads();
            gld16(a0 + k0, dA);
            gld16(b0 + k0, dB);
            __syncthreads();
            f16x8 af[4], bf[2];
            #pragma unroll
            for (int mi = 0; mi < 4; mi++)
                af[mi] = *(const f16x8*)&lA[(wm * 64 + mi * 16 + l16) * 32 + krh];
            #pragma unroll
            for (int ni = 0; ni < 2; ni++)
                bf[ni] = *(const f16x8*)&lB[(wn * 32 + ni * 16 + l16) * 32 + krh];
            #pragma unroll
            for (int mi = 0; mi < 4; mi++)
                #pragma unroll
                for (int ni = 0; ni < 2; ni++)
                    acc[mi][ni] = __builtin_amdgcn_mfma_f32_16x16x32_f16(af[mi], bf[ni], acc[mi][ni], 0, 0, 0);
        }
    };

    // Phase 0: acc = prev @ Wres^T          (K = 2048)
    phase(S16 + (long)m0 * DDIM, DDIM, Wr16 + (long)n0 * DDIM, DDIM, DDIM);
    // Phase 1: acc += X @ Win^T  -> u = ip + rp   (K = 512)
    phase(X16 + (long)m0 * IDIM, IDIM, Wc16 + (long)n0 * IDIM, IDIM, IDIM);
    #pragma unroll
    for (int mi = 0; mi < 4; mi++)
        #pragma unroll
        for (int ni = 0; ni < 2; ni++) { u[mi][ni] = acc[mi][ni]; acc[mi][ni] = (f32x4)0.0f; }

    // Phase 2: acc = X @ Wg_i^T  -> u = 0.2*tanh(sig(acc)*u)
    phase(X16 + (long)m0 * IDIM, IDIM, Wc16 + (long)(DDIM + n0) * IDIM, IDIM, IDIM);
    #pragma unroll
    for (int mi = 0; mi < 4; mi++)
        #pragma unroll
        for (int ni = 0; ni < 2; ni++) {
            #pragma unroll
            for (int r = 0; r < 4; r++)
                u[mi][ni][r] = 0.2f * tanhf(sigf(acc[mi][ni][r]) * u[mi][ni][r]);
            acc[mi][ni] = (f32x4)0.0f;
        }

    // Phase 3: acc = X @ Wg_f^T  -> u += 0.8*sig(acc)*prev
    phase(X16 + (long)m0 * IDIM, IDIM, Wc16 + (long)(2 * DDIM + n0) * IDIM, IDIM, IDIM);
    #pragma unroll
    for (int mi = 0; mi < 4; mi++)
        #pragma unroll
        for (int ni = 0; ni < 2; ni++) {
            #pragma unroll
            for (int r = 0; r < 4; r++) {
                int row = m0 + wm * 64 + mi * 16 + quad * 4 + r;
                int col = n0 + wn * 32 + ni * 16 + l16;
                float prev = state[(long)row * MAXD + col];
                u[mi][ni][r] += 0.8f * sigf(acc[mi][ni][r]) * prev;
            }
            acc[mi][ni] = (f32x4)0.0f;
        }

    // Phase 4: acc = X @ Wg_o^T  -> ns = sig(acc)*u -> spike -> write
    #pragma unroll
    for (int mi = 0; mi < 4; mi++)
        (void)0;
    phase(X16 + (long)m0 * IDIM, IDIM, Wc16 + (long)(3 * DDIM + n0) * IDIM, IDIM, IDIM);
    #pragma unroll
    for (int mi = 0; mi < 4; mi++)
        #pragma unroll
        for (int ni = 0; ni < 2; ni++) {
            #pragma unroll
            for (int r = 0; r < 4; r++) {
                int row = m0 + wm * 64 + mi * 16 + quad * 4 + r;
                int col = n0 + wn * 32 + ni * 16 + l16;
                float go = sigf(acc[mi][ni][r]);
                float ns = go * u[mi][ni][r];
                float ov = (ns > 0.5f) ? ns - 0.5f : ns;
                out[(long)row * MAXD + col] = ov;
                if (fabsf(ns - 0.5f) < BAND) {
                    unsigned pos = atomicAdd(&cntA[col], 1u);
                    if (pos < BCAP) {
                        bl[col * BCAP + pos] = (unsigned)row;
                    } else {
                        unsigned op = atomicAdd(&cntA[2048], 1u);
                        if (op < OCAP) ol[op] = (unsigned)((row << 11) | col);
                    }
                }
            }
        }
}

// ---------------------------------------------------------------------------
// fixup: exact fp64 recompute. 2048 blocks; block c loads col-c W-data
// (wres row 8KB + win/wg{i,f,o} rows 8KB) into LDS once, then 4 waves
// process that col's bucketed rows (10KB x+state reads each). Overflow
// entries (hot cols past BCAP) handled afterward via global W reads.
// ---------------------------------------------------------------------------
__global__ __launch_bounds__(256) void fixup_kernel(
    const float* __restrict__ x, const float* __restrict__ state,
    const float* __restrict__ win, const float* __restrict__ wres,
    const float* __restrict__ wgate,
    const unsigned* __restrict__ cntA, const unsigned* __restrict__ bl,
    const unsigned* __restrict__ ol, float* __restrict__ out)
{
    __shared__ float sWin[512], sWi[512], sWf[512], sWo[512];
    __shared__ float sWr[2048];
    const int c = blockIdx.x;
    const int t = threadIdx.x;
    const int wave = t >> 6, lane = t & 63;

    unsigned m = cntA[c]; if (m > BCAP) m = BCAP;
    if (m > 0) {
        for (int k = t; k < 512; k += 256) {
            sWin[k] = win[(long)c * IDIM + k];
            sWi[k]  = wgate[(long)c * IDIM + k];
            sWf[k]  = wgate[(long)(DDIM + c) * IDIM + k];
            sWo[k]  = wgate[(long)(2 * DDIM + c) * IDIM + k];
        }
        for (int k = t; k < 2048; k += 256)
            sWr[k] = wres[(long)c * DDIM + k];
        __syncthreads();

        for (unsigned e = wave; e < m; e += 4) {
            int row = (int)bl[c * BCAP + e];
            double ip = 0.0, gi = 0.0, gf = 0.0, go = 0.0, rp = 0.0;
            const float* xr = x + (long)row * IDIM;
            #pragma unroll 2
            for (int k = lane * 4; k < IDIM; k += 256) {
                float4 xv = *(const float4*)(xr + k);
                ip += (double)xv.x * (double)sWin[k]   + (double)xv.y * (double)sWin[k+1]
                    + (double)xv.z * (double)sWin[k+2] + (double)xv.w * (double)sWin[k+3];
                gi += (double)xv.x * (double)sWi[k]    + (double)xv.y * (double)sWi[k+1]
                    + (double)xv.z * (double)sWi[k+2]  + (double)xv.w * (double)sWi[k+3];
                gf += (double)xv.x * (double)sWf[k]    + (double)xv.y * (double)sWf[k+1]
                    + (double)xv.z * (double)sWf[k+2]  + (double)xv.w * (double)sWf[k+3];
                go += (double)xv.x * (double)sWo[k]    + (double)xv.y * (double)sWo[k+1]
                    + (double)xv.z * (double)sWo[k+2]  + (double)xv.w * (double)sWo[k+3];
            }
            const float* sr = state + (long)row * MAXD;
            #pragma unroll 4
            for (int k = lane * 4; k < DDIM; k += 256) {
                float4 sv = *(const float4*)(sr + k);
                rp += (double)sv.x * (double)sWr[k]   + (double)sv.y * (double)sWr[k+1]
                    + (double)sv.z * (double)sWr[k+2] + (double)sv.w * (double)sWr[k+3];
            }
            #pragma unroll
            for (int o = 32; o > 0; o >>= 1) {
                ip += __shfl_down(ip, o);
                gi += __shfl_down(gi, o);
                gf += __shfl_down(gf, o);
                go += __shfl_down(go, o);
                rp += __shfl_down(rp, o);
            }
            if (lane == 0) {
                double si = 1.0 / (1.0 + exp(-gi));
                double sf = 1.0 / (1.0 + exp(-gf));
                double so = 1.0 / (1.0 + exp(-go));
                double prev = (double)state[(long)row * MAXD + c];
                double ns = so * (0.8 * sf * prev + 0.2 * tanh(si * (ip + rp)));
                if (ns > 0.5) ns -= 0.5;
                out[(long)row * MAXD + c] = (float)ns;
            }
        }
    }

    // overflow entries (cols whose bucket filled) — global W reads, rare.
    unsigned nof = cntA[2048]; if (nof > OCAP) nof = OCAP;
    const int gw = blockIdx.x * 4 + wave;
    for (unsigned e = gw; e < nof; e += 2048 * 4) {
        unsigned rc = ol[e];
        int row = (int)(rc >> 11), col = (int)(rc & 2047);
        double ip = 0.0, gi = 0.0, gf = 0.0, go = 0.0, rp = 0.0;
        const float* xr  = x + (long)row * IDIM;
        const float* wi  = win + (long)col * IDIM;
        const float* wgi = wgate + (long)col * IDIM;
        const float* wgf = wgate + (long)(DDIM + col) * IDIM;
        const float* wgo = wgate + (long)(2 * DDIM + col) * IDIM;
        for (int k = lane * 4; k < IDIM; k += 256) {
            float4 xv = *(const float4*)(xr + k);
            float4 a = *(const float4*)(wi + k);
            float4 b = *(const float4*)(wgi + k);
            float4 cc = *(const float4*)(wgf + k);
            float4 d = *(const float4*)(wgo + k);
            ip += (double)xv.x * a.x + (double)xv.y * a.y + (double)xv.z * a.z + (double)xv.w * a.w;
            gi += (double)xv.x * b.x + (double)xv.y * b.y + (double)xv.z * b.z + (double)xv.w * b.w;
            gf += (double)xv.x * cc.x + (double)xv.y * cc.y + (double)xv.z * cc.z + (double)xv.w * cc.w;
            go += (double)xv.x * d.x + (double)xv.y * d.y + (double)xv.z * d.z + (double)xv.w * d.w;
        }
        const float* sr = state + (long)row * MAXD;
        const float* wr_ = wres + (long)col * DDIM;
        for (int k = lane * 4; k < DDIM; k += 256) {
            float4 sv = *(const float4*)(sr + k);
            float4 wv = *(const float4*)(wr_ + k);
            rp += (double)sv.x * wv.x + (double)sv.y * wv.y + (double)sv.z * wv.z + (double)sv.w * wv.w;
        }
        #pragma unroll
        for (int o = 32; o > 0; o >>= 1) {
            ip += __shfl_down(ip, o);
            gi += __shfl_down(gi, o);
            gf += __shfl_down(gf, o);
            go += __shfl_down(go, o);
            rp += __shfl_down(rp, o);
        }
        if (lane == 0) {
            double si = 1.0 / (1.0 + exp(-gi));
            double sf = 1.0 / (1.0 + exp(-gf));
            double so = 1.0 / (1.0 + exp(-go));
            double prev = (double)state[(long)row * MAXD + col];
            double ns = so * (0.8 * sf * prev + 0.2 * tanh(si * (ip + rp)));
            if (ns > 0.5) ns -= 0.5;
            out[(long)row * MAXD + col] = (float)ns;
        }
    }
}

extern "C" void kernel_launch(void* const* d_in, const int* in_sizes, int n_in,
                              void* d_out, int out_size, void* d_ws, size_t ws_size,
                              hipStream_t stream) {
    const float* x     = (const float*)d_in[0];   // (4096, 512)
    const float* state = (const float*)d_in[1];   // (4096, 2560)
    const float* win   = (const float*)d_in[2];   // (2048, 512)
    const float* wres  = (const float*)d_in[3];   // (2048, 2048)
    const float* wgate = (const float*)d_in[4];   // (6144, 512)
    float* out = (float*)d_out;

    char* ws = (char*)d_ws;
    unsigned short* X16  = (unsigned short*)(ws);                   //  0.. 4 MiB
    unsigned short* S16  = (unsigned short*)(ws + (4ll  << 20));    //  4..20
    unsigned short* Wc16 = (unsigned short*)(ws + (20ll << 20));    // 20..28
    unsigned short* Wr16 = (unsigned short*)(ws + (28ll << 20));    // 28..36
    unsigned* cntA = (unsigned*)(ws + (36ll << 20));                // 2052 u32 (16KB reserved)
    unsigned* bl   = (unsigned*)(ws + (36ll << 20) + (16ll << 10)); // 2048*96*4 = 768KB
    unsigned* ol   = (unsigned*)(ws + (37ll << 20));                // 1MB overflow

    convert_kernel<<<dim3(20480), dim3(256), 0, stream>>>(
        x, state, win, wgate, wres, X16, S16, Wc16, Wr16, out, cntA);

    fused_step<<<dim3(512), dim3(512), 0, stream>>>(
        X16, S16, Wc16, Wr16, state, out, cntA, bl, ol);

    fixup_kernel<<<dim3(2048), dim3(256), 0, stream>>>(
        x, state, win, wres, wgate, cntA, bl, ol, out);
}

// Round 15
// 321.239 us; speedup vs baseline: 1.1925x; 1.0473x over previous
//
#include <hip/hip_runtime.h>
#include <math.h>

// GatedSpikingReservoirStep — fp16-single MFMA fused kernel, in-kernel fp64 fixup.
// Round 21 = round 20 resubmit (container failed twice pre-run; audit found
// no divergent barriers, no unsatisfiable waits, LDS-list reuse sealed by
// sync, overflow path bounded — infra flake, and r12 proved resubmission
// works). Theory (r13): (1) fused 227->179us came from removing ~32k
// serialized atomicAdds on ONE global counter; (2) total-fused stayed
// ~157us through two independent fixup optimizations -> separate fixup
// dispatch is mostly overhead. This round FUSES the fp64 fixup into
// fused_step's tail: flagged (row,col) -> LDS list (reuse lA's 8KB after
// post-phase-4 sync; FCAP 2048 >> mean 64/block; global overflow + tiny
// sweep keeps correctness unconditional); 8 waves then cooperatively
// recompute each flagged element in fp64 from the original fp32 tensors
// (L2/L3-warm, ~2-3us/block, overlapped across blocks). GEMM structure =
// r13 exact (179us best: 128x128 tile, 512thr/8w, 64 VGPR, BK=32, r0
// swizzles, XCD chunks). Same fp64 formulas -> absmax unchanged.

#define IDIM 512
#define DDIM 2048
#define MAXD 2560
#define BDIM 4096
#define FCAP 2048
#define OCAP 262144
#define BAND 4e-3f

typedef __attribute__((ext_vector_type(4))) float f32x4;
typedef __attribute__((ext_vector_type(8))) _Float16 f16x8;

__device__ __forceinline__ void gld16(const unsigned short* g, unsigned short* l) {
    __builtin_amdgcn_global_load_lds((const __attribute__((address_space(1))) void*)g,
                                     (__attribute__((address_space(3))) void*)l,
                                     16, 0, 0);
}
__device__ __forceinline__ float sigf(float x) { return 1.0f / (1.0f + __expf(-x)); }

// ---------------------------------------------------------------------------
// convert: fp32 -> fp16 for X, S=state[:, :2048], Wc=[Win;Wgate], Wr;
// zero out-pad; zero overflow counter. 20480 blocks x 256 (float4 units).
// ---------------------------------------------------------------------------
__global__ __launch_bounds__(256) void convert_kernel(
    const float* __restrict__ x, const float* __restrict__ state,
    const float* __restrict__ win, const float* __restrict__ wgate,
    const float* __restrict__ wres,
    unsigned short* __restrict__ X16, unsigned short* __restrict__ S16,
    unsigned short* __restrict__ Wc16, unsigned short* __restrict__ Wr16,
    float* __restrict__ out, unsigned* __restrict__ cnt)
{
    int idx = blockIdx.x * 256 + threadIdx.x;
    if (idx == 0) *cnt = 0u;
    float4 v;
    unsigned short* p;
    long off;
    if (idx < 524288) {
        v = ((const float4*)x)[idx];
        p = X16; off = (long)idx * 4;
    } else if (idx < 2621440) {
        int i = idx - 524288;
        int row = i >> 9, c4 = i & 511;
        v = *(const float4*)(state + (long)row * MAXD + c4 * 4);
        p = S16; off = (long)i * 4;
    } else if (idx < 3670016) {
        int i = idx - 2621440;
        v = (i < 262144) ? ((const float4*)win)[i] : ((const float4*)wgate)[i - 262144];
        p = Wc16; off = (long)i * 4;
    } else if (idx < 4718592) {
        int i = idx - 3670016;
        v = ((const float4*)wres)[i];
        p = Wr16; off = (long)i * 4;
    } else {
        int i = idx - 4718592;
        int row = i >> 7, c4 = i & 127;
        *(float4*)(out + (long)row * MAXD + DDIM + c4 * 4) = make_float4(0.f, 0.f, 0.f, 0.f);
        return;
    }
    _Float16 h0 = (_Float16)v.x, h1 = (_Float16)v.y;
    _Float16 h2 = (_Float16)v.z, h3 = (_Float16)v.w;
    ushort4 hv;
    hv.x = *(unsigned short*)&h0; hv.y = *(unsigned short*)&h1;
    hv.z = *(unsigned short*)&h2; hv.w = *(unsigned short*)&h3;
    *(ushort4*)(p + off) = hv;
}

// ---------------------------------------------------------------------------
// fused_step: 5 GEMM phases + gating epilogue + IN-KERNEL fp64 fixup tail.
// GEMM = r13 exact. Tail: flagged (row,col) -> LDS list (lA reused, post-sync),
// then 8 waves cooperatively recompute each in fp64 from fp32 tensors.
// ---------------------------------------------------------------------------
__global__ __launch_bounds__(512, 4) void fused_step(
    const unsigned short* __restrict__ X16, const unsigned short* __restrict__ S16,
    const unsigned short* __restrict__ Wc16, const unsigned short* __restrict__ Wr16,
    const float* __restrict__ x, const float* __restrict__ state,
    const float* __restrict__ win, const float* __restrict__ wres,
    const float* __restrict__ wgate, float* __restrict__ out,
    unsigned* __restrict__ gcnt, unsigned* __restrict__ ol)
{
    __shared__ alignas(16) unsigned short lA[128 * 32];
    __shared__ alignas(16) unsigned short lB[128 * 32];
    __shared__ unsigned scnt;
    const int t = threadIdx.x;
    const int wave = t >> 6, lane = t & 63;
    const int wm = wave >> 2, wn = wave & 3;             // 2m x 4n wave grid
    const int quad = lane >> 4, l16 = lane & 15;
    if (t == 0) scnt = 0u;

    // bijective XCD swizzle: 512 blocks, tile grid 32m x 16n, 64 tiles/XCD
    const int bid = blockIdx.x;
    const int nb  = (bid & 7) * 64 + (bid >> 3);
    const int xcd = nb >> 6, lid = nb & 63;
    const int m0 = (((xcd >> 1) << 3) + (lid >> 3)) * 128;   // 32 m-tiles
    const int n0 = (((xcd & 1) << 3) + (lid & 7)) * 128;     // 16 n-tiles

    const int rowoff = lane >> 2;                         // 0..15
    const int kg = ((lane & 3) ^ ((lane >> 3) & 3)) * 8;  // write-side chunk swizzle (hw)
    const int krh = (quad ^ ((l16 >> 1) & 3)) * 8;        // read-side chunk (hw)

    f32x4 acc[4][2];
    f32x4 u[4][2];    // sum -> 0.2*tanh(i*sum) -> + 0.8*f*prev  (2 live sets)

    #pragma unroll
    for (int mi = 0; mi < 4; mi++)
        #pragma unroll
        for (int ni = 0; ni < 2; ni++)
            acc[mi][ni] = (f32x4)0.0f;

    auto phase = [&](const unsigned short* Ag, long ldA,
                     const unsigned short* Bg, long ldB, int klen) {
        const unsigned short* a0 = Ag + (long)(wave * 16 + rowoff) * ldA + kg;
        const unsigned short* b0 = Bg + (long)(wave * 16 + rowoff) * ldB + kg;
        unsigned short* dA = lA + wave * 512;             // 16 rows x 32 hw
        unsigned short* dB = lB + wave * 512;
        for (int k0 = 0; k0 < klen; k0 += 32) {
            __syncthreads();
            gld16(a0 + k0, dA);
            gld16(b0 + k0, dB);
            __syncthreads();
            f16x8 af[4], bf[2];
            #pragma unroll
            for (int mi = 0; mi < 4; mi++)
                af[mi] = *(const f16x8*)&lA[(wm * 64 + mi * 16 + l16) * 32 + krh];
            #pragma unroll
            for (int ni = 0; ni < 2; ni++)
                bf[ni] = *(const f16x8*)&lB[(wn * 32 + ni * 16 + l16) * 32 + krh];
            #pragma unroll
            for (int mi = 0; mi < 4; mi++)
                #pragma unroll
                for (int ni = 0; ni < 2; ni++)
                    acc[mi][ni] = __builtin_amdgcn_mfma_f32_16x16x32_f16(af[mi], bf[ni], acc[mi][ni], 0, 0, 0);
        }
    };

    // Phase 0: acc = prev @ Wres^T          (K = 2048)
    phase(S16 + (long)m0 * DDIM, DDIM, Wr16 + (long)n0 * DDIM, DDIM, DDIM);
    // Phase 1: acc += X @ Win^T  -> u = ip + rp   (K = 512)
    phase(X16 + (long)m0 * IDIM, IDIM, Wc16 + (long)n0 * IDIM, IDIM, IDIM);
    #pragma unroll
    for (int mi = 0; mi < 4; mi++)
        #pragma unroll
        for (int ni = 0; ni < 2; ni++) { u[mi][ni] = acc[mi][ni]; acc[mi][ni] = (f32x4)0.0f; }

    // Phase 2: acc = X @ Wg_i^T  -> u = 0.2*tanh(sig(acc)*u)
    phase(X16 + (long)m0 * IDIM, IDIM, Wc16 + (long)(DDIM + n0) * IDIM, IDIM, IDIM);
    #pragma unroll
    for (int mi = 0; mi < 4; mi++)
        #pragma unroll
        for (int ni = 0; ni < 2; ni++) {
            #pragma unroll
            for (int r = 0; r < 4; r++)
                u[mi][ni][r] = 0.2f * tanhf(sigf(acc[mi][ni][r]) * u[mi][ni][r]);
            acc[mi][ni] = (f32x4)0.0f;
        }

    // Phase 3: acc = X @ Wg_f^T  -> u += 0.8*sig(acc)*prev
    phase(X16 + (long)m0 * IDIM, IDIM, Wc16 + (long)(2 * DDIM + n0) * IDIM, IDIM, IDIM);
    #pragma unroll
    for (int mi = 0; mi < 4; mi++)
        #pragma unroll
        for (int ni = 0; ni < 2; ni++) {
            #pragma unroll
            for (int r = 0; r < 4; r++) {
                int row = m0 + wm * 64 + mi * 16 + quad * 4 + r;
                int col = n0 + wn * 32 + ni * 16 + l16;
                float prev = state[(long)row * MAXD + col];
                u[mi][ni][r] += 0.8f * sigf(acc[mi][ni][r]) * prev;
            }
            acc[mi][ni] = (f32x4)0.0f;
        }

    // Phase 4: acc = X @ Wg_o^T
    phase(X16 + (long)m0 * IDIM, IDIM, Wc16 + (long)(3 * DDIM + n0) * IDIM, IDIM, IDIM);

    // All lA/lB fragment reads are complete after this barrier; lA is then
    // safely reusable as the flagged-element list.
    __syncthreads();
    unsigned* flg = (unsigned*)lA;

    // Epilogue: ns = sig(acc)*u -> spike -> write; flag near-threshold.
    #pragma unroll
    for (int mi = 0; mi < 4; mi++)
        #pragma unroll
        for (int ni = 0; ni < 2; ni++) {
            #pragma unroll
            for (int r = 0; r < 4; r++) {
                int row = m0 + wm * 64 + mi * 16 + quad * 4 + r;
                int col = n0 + wn * 32 + ni * 16 + l16;
                float go = sigf(acc[mi][ni][r]);
                float ns = go * u[mi][ni][r];
                float ov = (ns > 0.5f) ? ns - 0.5f : ns;
                out[(long)row * MAXD + col] = ov;
                if (fabsf(ns - 0.5f) < BAND) {
                    unsigned pos = atomicAdd(&scnt, 1u);
                    if (pos < FCAP) {
                        flg[pos] = (unsigned)((row << 11) | col);
                    } else {
                        unsigned op = atomicAdd(gcnt, 1u);
                        if (op < OCAP) ol[op] = (unsigned)((row << 11) | col);
                    }
                }
            }
        }

    __syncthreads();
    unsigned nf = scnt; if (nf > FCAP) nf = FCAP;

    // fp64 fixup tail: waves cooperatively recompute flagged elements.
    for (unsigned e = wave; e < nf; e += 8) {
        unsigned rc = flg[e];
        int row = (int)(rc >> 11), col = (int)(rc & 2047);
        double ip = 0.0, gi = 0.0, gf = 0.0, go = 0.0, rp = 0.0;
        const float* xr  = x + (long)row * IDIM;
        const float* wi  = win + (long)col * IDIM;
        const float* wgi = wgate + (long)col * IDIM;
        const float* wgf = wgate + (long)(DDIM + col) * IDIM;
        const float* wgo = wgate + (long)(2 * DDIM + col) * IDIM;
        for (int k = lane * 4; k < IDIM; k += 256) {
            float4 xv = *(const float4*)(xr + k);
            float4 a = *(const float4*)(wi + k);
            float4 b = *(const float4*)(wgi + k);
            float4 c = *(const float4*)(wgf + k);
            float4 d = *(const float4*)(wgo + k);
            ip += (double)xv.x * a.x + (double)xv.y * a.y + (double)xv.z * a.z + (double)xv.w * a.w;
            gi += (double)xv.x * b.x + (double)xv.y * b.y + (double)xv.z * b.z + (double)xv.w * b.w;
            gf += (double)xv.x * c.x + (double)xv.y * c.y + (double)xv.z * c.z + (double)xv.w * c.w;
            go += (double)xv.x * d.x + (double)xv.y * d.y + (double)xv.z * d.z + (double)xv.w * d.w;
        }
        const float* sr = state + (long)row * MAXD;
        const float* wr_ = wres + (long)col * DDIM;
        for (int k = lane * 4; k < DDIM; k += 256) {
            float4 sv = *(const float4*)(sr + k);
            float4 wv = *(const float4*)(wr_ + k);
            rp += (double)sv.x * wv.x + (double)sv.y * wv.y + (double)sv.z * wv.z + (double)sv.w * wv.w;
        }
        #pragma unroll
        for (int o = 32; o > 0; o >>= 1) {
            ip += __shfl_down(ip, o);
            gi += __shfl_down(gi, o);
            gf += __shfl_down(gf, o);
            go += __shfl_down(go, o);
            rp += __shfl_down(rp, o);
        }
        if (lane == 0) {
            double si = 1.0 / (1.0 + exp(-gi));
            double sf = 1.0 / (1.0 + exp(-gf));
            double so = 1.0 / (1.0 + exp(-go));
            double prev = (double)state[(long)row * MAXD + col];
            double ns = so * (0.8 * sf * prev + 0.2 * tanh(si * (ip + rp)));
            if (ns > 0.5) ns -= 0.5;
            out[(long)row * MAXD + col] = (float)ns;
        }
    }
}

// ---------------------------------------------------------------------------
// overflow sweep: fp64 recompute for elements that overflowed a block's LDS
// list (expected 0). 128 blocks x 256; exits immediately when count is 0.
// ---------------------------------------------------------------------------
__global__ __launch_bounds__(256) void overflow_kernel(
    const float* __restrict__ x, const float* __restrict__ state,
    const float* __restrict__ win, const float* __restrict__ wres,
    const float* __restrict__ wgate,
    const unsigned* __restrict__ gcnt, const unsigned* __restrict__ ol,
    float* __restrict__ out)
{
    const int gwave = (blockIdx.x * 256 + threadIdx.x) >> 6;
    const int lane = threadIdx.x & 63;
    const int nwaves = gridDim.x * 4;
    unsigned n = *gcnt;
    if (n > OCAP) n = OCAP;
    for (unsigned e = gwave; e < n; e += nwaves) {
        unsigned rc = ol[e];
        int row = (int)(rc >> 11), col = (int)(rc & 2047);
        double ip = 0.0, gi = 0.0, gf = 0.0, go = 0.0, rp = 0.0;
        const float* xr  = x + (long)row * IDIM;
        const float* wi  = win + (long)col * IDIM;
        const float* wgi = wgate + (long)col * IDIM;
        const float* wgf = wgate + (long)(DDIM + col) * IDIM;
        const float* wgo = wgate + (long)(2 * DDIM + col) * IDIM;
        for (int k = lane * 4; k < IDIM; k += 256) {
            float4 xv = *(const float4*)(xr + k);
            float4 a = *(const float4*)(wi + k);
            float4 b = *(const float4*)(wgi + k);
            float4 c = *(const float4*)(wgf + k);
            float4 d = *(const float4*)(wgo + k);
            ip += (double)xv.x * a.x + (double)xv.y * a.y + (double)xv.z * a.z + (double)xv.w * a.w;
            gi += (double)xv.x * b.x + (double)xv.y * b.y + (double)xv.z * b.z + (double)xv.w * b.w;
            gf += (double)xv.x * c.x + (double)xv.y * c.y + (double)xv.z * c.z + (double)xv.w * c.w;
            go += (double)xv.x * d.x + (double)xv.y * d.y + (double)xv.z * d.z + (double)xv.w * d.w;
        }
        const float* sr = state + (long)row * MAXD;
        const float* wr_ = wres + (long)col * DDIM;
        for (int k = lane * 4; k < DDIM; k += 256) {
            float4 sv = *(const float4*)(sr + k);
            float4 wv = *(const float4*)(wr_ + k);
            rp += (double)sv.x * wv.x + (double)sv.y * wv.y + (double)sv.z * wv.z + (double)sv.w * wv.w;
        }
        #pragma unroll
        for (int o = 32; o > 0; o >>= 1) {
            ip += __shfl_down(ip, o);
            gi += __shfl_down(gi, o);
            gf += __shfl_down(gf, o);
            go += __shfl_down(go, o);
            rp += __shfl_down(rp, o);
        }
        if (lane == 0) {
            double si = 1.0 / (1.0 + exp(-gi));
            double sf = 1.0 / (1.0 + exp(-gf));
            double so = 1.0 / (1.0 + exp(-go));
            double prev = (double)state[(long)row * MAXD + col];
            double ns = so * (0.8 * sf * prev + 0.2 * tanh(si * (ip + rp)));
            if (ns > 0.5) ns -= 0.5;
            out[(long)row * MAXD + col] = (float)ns;
        }
    }
}

extern "C" void kernel_launch(void* const* d_in, const int* in_sizes, int n_in,
                              void* d_out, int out_size, void* d_ws, size_t ws_size,
                              hipStream_t stream) {
    const float* x     = (const float*)d_in[0];   // (4096, 512)
    const float* state = (const float*)d_in[1];   // (4096, 2560)
    const float* win   = (const float*)d_in[2];   // (2048, 512)
    const float* wres  = (const float*)d_in[3];   // (2048, 2048)
    const float* wgate = (const float*)d_in[4];   // (6144, 512)
    float* out = (float*)d_out;

    char* ws = (char*)d_ws;
    unsigned short* X16  = (unsigned short*)(ws);                   //  0.. 4 MiB
    unsigned short* S16  = (unsigned short*)(ws + (4ll  << 20));    //  4..20
    unsigned short* Wc16 = (unsigned short*)(ws + (20ll << 20));    // 20..28
    unsigned short* Wr16 = (unsigned short*)(ws + (28ll << 20));    // 28..36
    unsigned* gcnt = (unsigned*)(ws + (36ll << 20));                // 4 B
    unsigned* ol   = (unsigned*)(ws + (36ll << 20) + 16);           // 1 MiB

    convert_kernel<<<dim3(20480), dim3(256), 0, stream>>>(
        x, state, win, wgate, wres, X16, S16, Wc16, Wr16, out, gcnt);

    fused_step<<<dim3(512), dim3(512), 0, stream>>>(
        X16, S16, Wc16, Wr16, x, state, win, wres, wgate, out, gcnt, ol);

    overflow_kernel<<<dim3(128), dim3(256), 0, stream>>>(
        x, state, win, wres, wgate, gcnt, ol, out);
}